// Round 8
// baseline (130.671 us; speedup 1.0000x reference)
//
#include <hip/hip_runtime.h>
#include <hip/hip_bf16.h>
#include <stdint.h>

#define NEG_INF -9.0e15f
#define LRELU_ALPHA 0.2f
#define LOG2E 1.442695040888963f

using bf16x8  = __attribute__((ext_vector_type(8))) short;
using f32x4   = __attribute__((ext_vector_type(4))) float;
using short4v = __attribute__((ext_vector_type(4))) short;
using int4v   = __attribute__((ext_vector_type(4))) int;
using float4v = __attribute__((ext_vector_type(4))) float;
using uint4v  = __attribute__((ext_vector_type(4))) unsigned;

static __device__ __forceinline__ float b2f(short s) {
  unsigned u = ((unsigned)(unsigned short)s) << 16;
  return __builtin_bit_cast(float, u);
}
static __device__ __forceinline__ short f2bf(float f) {
  unsigned u = __builtin_bit_cast(unsigned, f);
  u = u + 0x7FFFu + ((u >> 16) & 1u);   // RNE
  return (short)(u >> 16);
}
// pack two f32 -> one dword of 2 bf16 (RNE), gfx950 v_cvt_pk_bf16_f32
static __device__ __forceinline__ unsigned cvtpk_bf16(float lo, float hi) {
  unsigned r;
  asm volatile("v_cvt_pk_bf16_f32 %0, %1, %2" : "=v"(r) : "v"(lo), "v"(hi));
  return r;
}
static __device__ __forceinline__ void gload16(const void* g, void* l) {
  __builtin_amdgcn_global_load_lds((const __attribute__((address_space(1))) void*)g,
                                   (__attribute__((address_space(3))) void*)l, 16, 0, 0);
}

// ---------------- W (f32, 256x256) -> W^T (bf16) in one pass ----------------
__global__ __launch_bounds__(256) void castT_W_kernel(
    const float* __restrict__ src, short* __restrict__ dst)
{
  __shared__ float t[64][65];
  const int m0 = blockIdx.x * 64, n0 = blockIdx.y * 64;
  const int tid = threadIdx.x;
  const int rr = tid >> 3, cc = (tid & 7) * 8;
#pragma unroll
  for (int p = 0; p < 2; ++p) {
    int row = rr + p * 32;
    const float* sp = src + (m0 + row) * 256 + n0 + cc;
    float4v v0 = *(const float4v*)sp;
    float4v v1 = *(const float4v*)(sp + 4);
#pragma unroll
    for (int j = 0; j < 4; ++j) { t[row][cc + j] = v0[j]; t[row][cc + 4 + j] = v1[j]; }
  }
  __syncthreads();
#pragma unroll
  for (int p = 0; p < 2; ++p) {
    int orow = rr + p * 32;
    short vv[8] __attribute__((aligned(16)));
#pragma unroll
    for (int j = 0; j < 8; ++j) vv[j] = f2bf(t[cc + j][orow]);
    short* dp = dst + (n0 + orow) * 256 + m0 + cc;
    *(int4v*)dp = *(const int4v*)vv;
  }
}

// ---------------- transpose (bf16), 64x64 LDS tiles (for Wh -> Wh_t) ----------------
__global__ __launch_bounds__(256) void transpose_bf16_kernel(
    const short* __restrict__ src, short* __restrict__ dst,
    int M, int N, long long ss, long long ds)
{
  __shared__ short t[64][68];
  const int b = blockIdx.z;
  src += (long long)b * ss; dst += (long long)b * ds;
  const int m0 = blockIdx.x * 64, n0 = blockIdx.y * 64;
  const int tid = threadIdx.x;
  const int rr = tid >> 3, cc = (tid & 7) * 8;
#pragma unroll
  for (int p = 0; p < 2; ++p) {
    int row = rr + p * 32;
    const short* sp = src + (long long)(m0 + row) * N + n0 + cc;
    short4v v0 = *(const short4v*)sp;
    short4v v1 = *(const short4v*)(sp + 4);
    *(short4v*)&t[row][cc]     = v0;
    *(short4v*)&t[row][cc + 4] = v1;
  }
  __syncthreads();
#pragma unroll
  for (int p = 0; p < 2; ++p) {
    int orow = rr + p * 32;
    short vv[8] __attribute__((aligned(16)));
#pragma unroll
    for (int j = 0; j < 8; ++j) vv[j] = t[cc + j][orow];
    short* dp = dst + (long long)(n0 + orow) * M + m0 + cc;
    *(int4v*)dp = *(const int4v*)vv;
  }
}

// ---------------- e1/e2 = Wh @ a1/a2 (one wave per row); a is f32 ----------------
__global__ __launch_bounds__(256) void evec_kernel(
    const short* __restrict__ Wh, const float* __restrict__ a,
    float* __restrict__ e1, float* __restrict__ e2)
{
  const int wid = threadIdx.x >> 6, lane = threadIdx.x & 63;
  const long long r = (long long)blockIdx.x * 4 + wid;
  short4v hv   = *(const short4v*)(Wh + r * 256 + lane * 4);
  float4v a1v  = *(const float4v*)(a + lane * 4);
  float4v a2v  = *(const float4v*)(a + 256 + lane * 4);
  float s1 = 0.f, s2 = 0.f;
#pragma unroll
  for (int k = 0; k < 4; ++k) {
    float x = b2f(hv[k]);
    s1 += x * a1v[k];
    s2 += x * a2v[k];
  }
#pragma unroll
  for (int off = 32; off > 0; off >>= 1) {
    s1 += __shfl_xor(s1, off, 64);
    s2 += __shfl_xor(s2, off, 64);
  }
  if (lane == 0) { e1[r] = s1; e2[r] = s2; }
}

// ------- mask + leakyrelu + softmax -> attention (f32, BW-roofline, round-5 proven)
//         PLUS bitmask + per-row recompute consts (L,D) for the pv kernel -------
// P[i,j] = bit ? exp2(lrelu(e1_i+e2_j)*L_i + D_i) : 0;  L=log2e, D=-M*log2e-log2(S).
// Empty row: uniform 1/2048 (matches reference); mask=0xFF, L=0, D=-11.
__global__ __launch_bounds__(256) void attn_softmax_kernel(
    const int* __restrict__ adj, const float* __restrict__ e1,
    const float* __restrict__ e2, float* __restrict__ attn,
    unsigned char* __restrict__ mask, float* __restrict__ Lr, float* __restrict__ Dr)
{
  const int i = blockIdx.x;
  const int b = blockIdx.y;
  const long long row = (long long)b * 2048 + i;
  const int tid = threadIdx.x;
  const int wid = tid >> 6, lane = tid & 63;
  const int j0 = tid * 8;

  const int*   arow = adj + row * 2048 + j0;
  const float  ei   = e1[row];
  const float* e2b  = e2 + b * 2048 + j0;

  int4v   a0 = *(const int4v*)(arow);
  int4v   a1 = *(const int4v*)(arow + 4);
  float4v f0 = *(const float4v*)(e2b);
  float4v f1 = *(const float4v*)(e2b + 4);

  float s[8]; unsigned byte = 0u;
#pragma unroll
  for (int k = 0; k < 8; ++k) {
    float x = ei + (k < 4 ? f0[k] : f1[k - 4]);
    float v = fmaxf(x, LRELU_ALPHA * x);
    int  ad = (k < 4 ? a0[k] : a1[k - 4]);
    if (ad > 0) { s[k] = v; byte |= (1u << k); } else s[k] = NEG_INF;
  }
  float m = s[0];
#pragma unroll
  for (int k = 1; k < 8; ++k) m = fmaxf(m, s[k]);
#pragma unroll
  for (int off = 32; off > 0; off >>= 1) m = fmaxf(m, __shfl_xor(m, off, 64));

  __shared__ float wmax[4], wsum[4];
  if (lane == 0) wmax[wid] = m;
  __syncthreads();
  const float M = fmaxf(fmaxf(wmax[0], wmax[1]), fmaxf(wmax[2], wmax[3]));
  const bool empty = (M == NEG_INF);

  mask[row * 256 + tid] = empty ? (unsigned char)0xFF : (unsigned char)byte;

  float p[8]; float t = 0.f;
#pragma unroll
  for (int k = 0; k < 8; ++k) { p[k] = __expf(s[k] - M); t += p[k]; }  // empty: exp(0)=1
#pragma unroll
  for (int off = 32; off > 0; off >>= 1) t += __shfl_xor(t, off, 64);
  if (lane == 0) wsum[wid] = t;
  __syncthreads();
  const float S = wsum[0] + wsum[1] + wsum[2] + wsum[3];
  const float r = 1.0f / S;

  if (tid == 0) {
    Lr[row] = empty ? 0.0f : LOG2E;
    Dr[row] = empty ? -11.0f : (-M * LOG2E - __log2f(S));
  }

  float4v o0, o1;
#pragma unroll
  for (int k = 0; k < 4; ++k) { o0[k] = p[k] * r; o1[k] = p[k + 4] * r; }
  float* op = attn + row * 2048 + j0;
  *(float4v*)op       = o0;
  *(float4v*)(op + 4) = o1;
}

// ------------- pv: recompute-P (from mask + consts) @ Wh_t + ELU -> hp_out -------------
// Round-7 fused_pv with the in-loop attention stores REMOVED (they forced a
// store-completion drain at every barrier). No global stores in the K-loop.
// Block = 32 rows x 256 cols, BK=64, 4 waves; As (P bf16, chunk-XOR swz),
// Bs via global_load_lds (pre-swizzled source, chunk ^ (col&7)). XCD-pinned bz=bid&7.
__global__ __launch_bounds__(256, 2) void pv_kernel(
    const unsigned char* __restrict__ mask, const float* __restrict__ e1,
    const float* __restrict__ e2, const float* __restrict__ Lr,
    const float* __restrict__ Dr, const short* __restrict__ Bt,
    float* __restrict__ C)
{
  __shared__ short As[32 * 64];     // 4 KB
  __shared__ short Bs[256 * 64];    // 32 KB
  const int bid = blockIdx.x;
  const int bz  = bid & 7;
  const int M0  = (bid >> 3) << 5;
  const int tid = threadIdx.x;
  const int w = tid >> 6, lane = tid & 63;
  const int g = lane >> 4, lr = lane & 15;

  const long long rb = (long long)bz * 2048;
  Bt += (long long)bz * 524288;
  C  += (long long)bz * 524288;

  // P-stage identities: thread (pr, kc8) computes 8 P values once per K-step
  const int pr = tid >> 3, kc8 = tid & 7;
  const int prow = M0 + pr;
  const float E1p = e1[rb + prow];
  const float Lp  = Lr[rb + prow];
  const float Dp  = Dr[rb + prow];
  const unsigned char* mrow = mask + (rb + prow) * 256;
  short* as_wr = As + pr * 64 + ((kc8 ^ (pr & 7)) << 3);
  const float* e2b = e2 + rb;

  const int bcol_off = lane >> 3;
  const int bchunk   = (lane & 7) ^ ((lane >> 3) & 7);

  f32x4 acc[2][4] = {};

  for (int k0 = 0; k0 < 2048; k0 += 64) {
    __syncthreads();                       // prev-iter LDS reads done
    // --- P-stage: 8 values/thread, once; LDS only, no global stores ---
    {
      const unsigned by = mrow[(k0 >> 3) + kc8];
      const int kk = k0 + kc8 * 8;
      float4v eo = *(const float4v*)(e2b + kk);
      float4v eh = *(const float4v*)(e2b + kk + 4);
      float p[8];
#pragma unroll
      for (int e = 0; e < 8; ++e) {
        float x = E1p + (e < 4 ? eo[e] : eh[e - 4]);
        float v = fmaxf(x, LRELU_ALPHA * x);
        float P = __builtin_amdgcn_exp2f(fmaf(v, Lp, Dp));
        p[e] = ((by >> e) & 1u) ? P : 0.0f;
      }
      uint4v uv;
      uv[0] = cvtpk_bf16(p[0], p[1]);
      uv[1] = cvtpk_bf16(p[2], p[3]);
      uv[2] = cvtpk_bf16(p[4], p[5]);
      uv[3] = cvtpk_bf16(p[6], p[7]);
      *(bf16x8*)as_wr = __builtin_bit_cast(bf16x8, uv);
    }
    // --- B-stage: 256x64 bf16, 32 wave-issues of 1 KB ---
#pragma unroll
    for (int q = 0; q < 8; ++q) {
      int pp = w * 8 + q;
      int col = pp * 8 + bcol_off;
      gload16(Bt + (long long)col * 2048 + k0 + bchunk * 8, Bs + pp * 512);
    }
    __syncthreads();                       // drains ds_write + B lds-DMA only

    bf16x8 af[2][2], bfr[4][2];
#pragma unroll
    for (int i = 0; i < 2; ++i) {
      int row = i * 16 + lr;
#pragma unroll
      for (int s = 0; s < 2; ++s)
        af[i][s] = *(const bf16x8*)(As + row * 64 + (((s * 4 + g) ^ (row & 7)) << 3));
    }
#pragma unroll
    for (int j = 0; j < 4; ++j) {
      int col = w * 64 + j * 16 + lr;
#pragma unroll
      for (int s = 0; s < 2; ++s)
        bfr[j][s] = *(const bf16x8*)(Bs + col * 64 + (((s * 4 + g) ^ (col & 7)) << 3));
    }
#pragma unroll
    for (int s = 0; s < 2; ++s)
#pragma unroll
      for (int i = 0; i < 2; ++i)
#pragma unroll
        for (int j = 0; j < 4; ++j)
          acc[i][j] = __builtin_amdgcn_mfma_f32_16x16x32_bf16(af[i][s], bfr[j][s], acc[i][j], 0, 0, 0);
  }

  // C/D: col=lane&15, row=(lane>>4)*4+reg  [m89]
#pragma unroll
  for (int i = 0; i < 2; ++i) {
    int row_base = M0 + i * 16 + 4 * g;
#pragma unroll
    for (int j = 0; j < 4; ++j) {
      int col = w * 64 + j * 16 + lr;
#pragma unroll
      for (int r = 0; r < 4; ++r) {
        float v = acc[i][j][r];
        v = (v > 0.f) ? v : (__expf(v) - 1.f);   // ELU
        C[(long long)(row_base + r) * 256 + col] = v;
      }
    }
  }
}

// ------------- Wh = cast(h_f32) @ W_t^T : m97 structure, A reg-staged f32->bf16 -------------
__global__ __launch_bounds__(256) void gemm_h_kernel(
    const float* __restrict__ A, const short* __restrict__ Bt,
    short* __restrict__ C, int N, int K)
{
  __shared__ short As[128 * 32];
  __shared__ short Bs[128 * 32];
  const int m0 = blockIdx.x * 128, n0 = blockIdx.y * 128;
  const int tid = threadIdx.x;
  const int w = tid >> 6, lane = tid & 63;
  const int wr = w >> 1, wc = w & 1;
  const int g = lane >> 4, lr = lane & 15;

  f32x4 acc[4][4] = {};

  for (int k0 = 0; k0 < K; k0 += 32) {
    __syncthreads();
#pragma unroll
    for (int q = 0; q < 2; ++q) {
      int c = q * 256 + tid;
      int row = c >> 2, kq = (c & 3) << 3;
      const float* ap = A + (long long)(m0 + row) * K + k0 + kq;
      float4v u0 = *(const float4v*)ap;
      float4v u1 = *(const float4v*)(ap + 4);
      uint4v uv;
      uv[0] = cvtpk_bf16(u0[0], u0[1]);
      uv[1] = cvtpk_bf16(u0[2], u0[3]);
      uv[2] = cvtpk_bf16(u1[0], u1[1]);
      uv[3] = cvtpk_bf16(u1[2], u1[3]);
      *(bf16x8*)(As + c * 8) = __builtin_bit_cast(bf16x8, uv);
    }
#pragma unroll
    for (int q = 0; q < 2; ++q) {
      int p = w * 2 + q;
      int c = p * 64 + lane;
      int row = c >> 2, kq = (c & 3) << 3;
      gload16(Bt + (long long)(n0 + row) * K + k0 + kq, Bs + p * 512);
    }
    __syncthreads();

    bf16x8 af[4], bfr[4];
#pragma unroll
    for (int i = 0; i < 4; ++i) {
      af[i]  = *(const bf16x8*)(As + (wr * 64 + i * 16 + lr) * 32 + 8 * g);
      bfr[i] = *(const bf16x8*)(Bs + (wc * 64 + i * 16 + lr) * 32 + 8 * g);
    }
#pragma unroll
    for (int i = 0; i < 4; ++i)
#pragma unroll
      for (int j = 0; j < 4; ++j)
        acc[i][j] = __builtin_amdgcn_mfma_f32_16x16x32_bf16(af[i], bfr[j], acc[i][j], 0, 0, 0);
  }

#pragma unroll
  for (int i = 0; i < 4; ++i) {
    int row_base = m0 + wr * 64 + i * 16 + 4 * g;
#pragma unroll
    for (int j = 0; j < 4; ++j) {
      int col = n0 + wc * 64 + j * 16 + lr;
#pragma unroll
      for (int r = 0; r < 4; ++r)
        C[(long long)(row_base + r) * N + col] = f2bf(acc[i][j][r]);
    }
  }
}

extern "C" void kernel_launch(void* const* d_in, const int* in_sizes, int n_in,
                              void* d_out, int out_size, void* d_ws, size_t ws_size,
                              hipStream_t stream)
{
  const float* h   = (const float*)d_in[0];   // (8,2048,256) f32
  const int*   adj = (const int*)d_in[1];     // (8,2048,2048) int32
  const float* W   = (const float*)d_in[2];   // (256,256) f32
  const float* a   = (const float*)d_in[3];   // (512,1) f32

  float* hp_out   = (float*)d_out;            // elu(h_prime): 4,194,304 f32
  float* attn_out = hp_out + 4194304LL;       // attention: 33,554,432 f32

  // workspace: 21.4 MB (proven-OK layout)
  unsigned char* mask = (unsigned char*)d_ws; // 8*2048*256 = 4.19 MB
  short* W_t  = (short*)(mask + 4194304);     // 256x256 bf16
  short* Wh   = W_t + 65536;                  // 16384x256 bf16
  short* Wh_t = Wh + 4194304;                 // 8 x (256x2048) bf16
  float* e1   = (float*)(Wh_t + 4194304);     // 16384
  float* e2   = e1 + 16384;                   // 16384
  float* Lr   = e2 + 16384;                   // 16384
  float* Dr   = Lr + 16384;                   // 16384

  // 1) W f32 -> W^T bf16
  castT_W_kernel<<<dim3(4, 4), 256, 0, stream>>>(W, W_t);
  // 2) Wh = cast(h) @ W (cast fused into A-staging)
  gemm_h_kernel<<<dim3(128, 2, 1), 256, 0, stream>>>(h, W_t, Wh, 256, 256);
  // 3) Wh^T per batch (2048x256 -> 256x2048)
  transpose_bf16_kernel<<<dim3(32, 4, 8), 256, 0, stream>>>(Wh, Wh_t, 2048, 256, 524288LL, 524288LL);
  // 4) e1/e2
  evec_kernel<<<4096, 256, 0, stream>>>(Wh, a, e1, e2);
  // 5) softmax -> attention (BW-roofline) + mask + (L,D)
  attn_softmax_kernel<<<dim3(2048, 8), 256, 0, stream>>>(adj, e1, e2, attn_out, mask, Lr, Dr);
  // 6) pv: recompute P from mask, P @ Wh_t + ELU (no global stores in loop)
  pv_kernel<<<512, 256, 0, stream>>>(mask, e1, e2, Lr, Dr, Wh_t, hp_out);
}

// Round 9
// 120.628 us; speedup vs baseline: 1.0833x; 1.0833x over previous
//
#include <hip/hip_runtime.h>
#include <hip/hip_bf16.h>
#include <stdint.h>

#define NEG_INF -9.0e15f
#define LRELU_ALPHA 0.2f
#define LOG2E 1.442695040888963f

using bf16x8  = __attribute__((ext_vector_type(8))) short;
using f32x4   = __attribute__((ext_vector_type(4))) float;
using short4v = __attribute__((ext_vector_type(4))) short;
using int4v   = __attribute__((ext_vector_type(4))) int;
using float4v = __attribute__((ext_vector_type(4))) float;
using uint4v  = __attribute__((ext_vector_type(4))) unsigned;

static __device__ __forceinline__ float b2f(short s) {
  unsigned u = ((unsigned)(unsigned short)s) << 16;
  return __builtin_bit_cast(float, u);
}
static __device__ __forceinline__ short f2bf(float f) {
  unsigned u = __builtin_bit_cast(unsigned, f);
  u = u + 0x7FFFu + ((u >> 16) & 1u);   // RNE
  return (short)(u >> 16);
}
static __device__ __forceinline__ unsigned cvtpk_bf16(float lo, float hi) {
  unsigned r;
  asm volatile("v_cvt_pk_bf16_f32 %0, %1, %2" : "=v"(r) : "v"(lo), "v"(hi));
  return r;
}
static __device__ __forceinline__ void gload16(const void* g, void* l) {
  __builtin_amdgcn_global_load_lds((const __attribute__((address_space(1))) void*)g,
                                   (__attribute__((address_space(3))) void*)l, 16, 0, 0);
}

// ---------------- W (f32, 256x256) -> W^T (bf16) in one pass ----------------
__global__ __launch_bounds__(256) void castT_W_kernel(
    const float* __restrict__ src, short* __restrict__ dst)
{
  __shared__ float t[64][65];
  const int m0 = blockIdx.x * 64, n0 = blockIdx.y * 64;
  const int tid = threadIdx.x;
  const int rr = tid >> 3, cc = (tid & 7) * 8;
#pragma unroll
  for (int p = 0; p < 2; ++p) {
    int row = rr + p * 32;
    const float* sp = src + (m0 + row) * 256 + n0 + cc;
    float4v v0 = *(const float4v*)sp;
    float4v v1 = *(const float4v*)(sp + 4);
#pragma unroll
    for (int j = 0; j < 4; ++j) { t[row][cc + j] = v0[j]; t[row][cc + 4 + j] = v1[j]; }
  }
  __syncthreads();
#pragma unroll
  for (int p = 0; p < 2; ++p) {
    int orow = rr + p * 32;
    short vv[8] __attribute__((aligned(16)));
#pragma unroll
    for (int j = 0; j < 8; ++j) vv[j] = f2bf(t[cc + j][orow]);
    short* dp = dst + (n0 + orow) * 256 + m0 + cc;
    *(int4v*)dp = *(const int4v*)vv;
  }
}

// ---------------- transpose (bf16), 64x64 LDS tiles (for Wh -> Wh_t) ----------------
__global__ __launch_bounds__(256) void transpose_bf16_kernel(
    const short* __restrict__ src, short* __restrict__ dst,
    int M, int N, long long ss, long long ds)
{
  __shared__ short t[64][68];
  const int b = blockIdx.z;
  src += (long long)b * ss; dst += (long long)b * ds;
  const int m0 = blockIdx.x * 64, n0 = blockIdx.y * 64;
  const int tid = threadIdx.x;
  const int rr = tid >> 3, cc = (tid & 7) * 8;
#pragma unroll
  for (int p = 0; p < 2; ++p) {
    int row = rr + p * 32;
    const short* sp = src + (long long)(m0 + row) * N + n0 + cc;
    short4v v0 = *(const short4v*)sp;
    short4v v1 = *(const short4v*)(sp + 4);
    *(short4v*)&t[row][cc]     = v0;
    *(short4v*)&t[row][cc + 4] = v1;
  }
  __syncthreads();
#pragma unroll
  for (int p = 0; p < 2; ++p) {
    int orow = rr + p * 32;
    short vv[8] __attribute__((aligned(16)));
#pragma unroll
    for (int j = 0; j < 8; ++j) vv[j] = t[cc + j][orow];
    short* dp = dst + (long long)(n0 + orow) * M + m0 + cc;
    *(int4v*)dp = *(const int4v*)vv;
  }
}

// ---------------- e1/e2 = Wh @ a1/a2 (one wave per row); a is f32 ----------------
__global__ __launch_bounds__(256) void evec_kernel(
    const short* __restrict__ Wh, const float* __restrict__ a,
    float* __restrict__ e1, float* __restrict__ e2)
{
  const int wid = threadIdx.x >> 6, lane = threadIdx.x & 63;
  const long long r = (long long)blockIdx.x * 4 + wid;
  short4v hv   = *(const short4v*)(Wh + r * 256 + lane * 4);
  float4v a1v  = *(const float4v*)(a + lane * 4);
  float4v a2v  = *(const float4v*)(a + 256 + lane * 4);
  float s1 = 0.f, s2 = 0.f;
#pragma unroll
  for (int k = 0; k < 4; ++k) {
    float x = b2f(hv[k]);
    s1 += x * a1v[k];
    s2 += x * a2v[k];
  }
#pragma unroll
  for (int off = 32; off > 0; off >>= 1) {
    s1 += __shfl_xor(s1, off, 64);
    s2 += __shfl_xor(s2, off, 64);
  }
  if (lane == 0) { e1[r] = s1; e2[r] = s2; }
}

// ------------- pass 1: adj -> bitmask + per-row softmax consts (R7-verified) -------------
// P[i,j] = bit ? exp2(lrelu(e1_i+e2_j)*L_i + D_i) : 0;  L=log2e, D=-M*log2e-log2(S).
// Empty row: uniform 1/2048 -> mask=0xFF, L=0, D=-11.
__global__ __launch_bounds__(256) void pack_stats_kernel(
    const int* __restrict__ adj, const float* __restrict__ e1,
    const float* __restrict__ e2, unsigned char* __restrict__ mask,
    float* __restrict__ Lr, float* __restrict__ Dr)
{
  const int i = blockIdx.x;
  const int b = blockIdx.y;
  const long long row = (long long)b * 2048 + i;
  const int tid = threadIdx.x;
  const int wid = tid >> 6, lane = tid & 63;
  const int j0 = tid * 8;

  const int*   arow = adj + row * 2048 + j0;
  const float  ei   = e1[row];
  const float* e2b  = e2 + b * 2048 + j0;

  int4v   a0 = *(const int4v*)(arow);
  int4v   a1 = *(const int4v*)(arow + 4);
  float4v f0 = *(const float4v*)(e2b);
  float4v f1 = *(const float4v*)(e2b + 4);

  float s[8]; unsigned byte = 0u;
#pragma unroll
  for (int k = 0; k < 8; ++k) {
    float x = ei + (k < 4 ? f0[k] : f1[k - 4]);
    float v = fmaxf(x, LRELU_ALPHA * x);
    int  ad = (k < 4 ? a0[k] : a1[k - 4]);
    if (ad > 0) { s[k] = v; byte |= (1u << k); } else s[k] = NEG_INF;
  }
  float m = s[0];
#pragma unroll
  for (int k = 1; k < 8; ++k) m = fmaxf(m, s[k]);
#pragma unroll
  for (int off = 32; off > 0; off >>= 1) m = fmaxf(m, __shfl_xor(m, off, 64));

  __shared__ float wmax[4], wsum[4];
  if (lane == 0) wmax[wid] = m;
  __syncthreads();
  const float M = fmaxf(fmaxf(wmax[0], wmax[1]), fmaxf(wmax[2], wmax[3]));
  const bool empty = (M == NEG_INF);

  mask[row * 256 + tid] = empty ? (unsigned char)0xFF : (unsigned char)byte;

  float t = 0.f;
#pragma unroll
  for (int k = 0; k < 8; ++k) t += __expf(s[k] - M);
#pragma unroll
  for (int off = 32; off > 0; off >>= 1) t += __shfl_xor(t, off, 64);
  if (lane == 0) wsum[wid] = t;
  __syncthreads();
  if (tid == 0) {
    const float S = wsum[0] + wsum[1] + wsum[2] + wsum[3];
    Lr[row] = empty ? 0.0f : LOG2E;
    Dr[row] = empty ? -11.0f : (-M * LOG2E - __log2f(S));
  }
}

// ------------- pass 2: pipelined recompute-P -> {attention write, P @ Wh_t + ELU} ----------
// 2-phase software pipeline (m248 template): STAGE(t+1) issued BEFORE COMPUTE(t),
// double-buffered As/Bs (72 KB), ONE barrier per K-step. B gload16s issue first;
// the P VALU chain + attention stores hide under their L2 latency; MFMA covers the rest.
// Arithmetic identical to verified R7 fused_pv (attn stores in-loop = proven free).
__global__ __launch_bounds__(256, 2) void pv_kernel(
    const unsigned char* __restrict__ mask, const float* __restrict__ e1,
    const float* __restrict__ e2, const float* __restrict__ Lr,
    const float* __restrict__ Dr, const short* __restrict__ Bt,
    float* __restrict__ attnw, float* __restrict__ C)
{
  __shared__ short As0[32 * 64],  As1[32 * 64];     // 2 x 4 KB
  __shared__ short Bs0[256 * 64], Bs1[256 * 64];    // 2 x 32 KB
  const int bid = blockIdx.x;
  const int bz  = bid & 7;          // XCD-pinned batch
  const int M0  = (bid >> 3) << 5;
  const int tid = threadIdx.x;
  const int w = tid >> 6, lane = tid & 63;
  const int g = lane >> 4, lr = lane & 15;

  const long long rb = (long long)bz * 2048;
  Bt    += (long long)bz * 524288;
  attnw += (long long)bz * 4194304;
  C     += (long long)bz * 524288;

  // P-stage identities: thread (pr, kc8) computes 8 P values once per K-step
  const int pr = tid >> 3, kc8 = tid & 7;
  const int prow = M0 + pr;
  const float E1p = e1[rb + prow];
  const float Lp  = Lr[rb + prow];
  const float Dp  = Dr[rb + prow];
  const unsigned char* mrow = mask + (rb + prow) * 256;
  float* arow = attnw + (long long)prow * 2048;
  const int as_off = pr * 64 + ((kc8 ^ (pr & 7)) << 3);
  const float* e2b = e2 + rb;

  const int bcol_off = lane >> 3;
  const int bchunk   = (lane & 7) ^ ((lane >> 3) & 7);

  f32x4 acc[2][4] = {};

  auto STAGE = [&](short* BsD, short* AsD, int k0) {
    // B first: get the 8 DMA loads in flight ASAP
#pragma unroll
    for (int q = 0; q < 8; ++q) {
      int pp = w * 8 + q;
      int col = pp * 8 + bcol_off;
      gload16(Bt + (long long)col * 2048 + k0 + bchunk * 8, BsD + pp * 512);
    }
    // P: VALU + attention store, overlapping B latency
    const unsigned by = mrow[(k0 >> 3) + kc8];
    const int kk = k0 + kc8 * 8;
    float4v eo = *(const float4v*)(e2b + kk);
    float4v eh = *(const float4v*)(e2b + kk + 4);
    float p[8];
#pragma unroll
    for (int e = 0; e < 8; ++e) {
      float x = E1p + (e < 4 ? eo[e] : eh[e - 4]);
      float v = fmaxf(x, LRELU_ALPHA * x);
      float P = __builtin_amdgcn_exp2f(fmaf(v, Lp, Dp));
      p[e] = ((by >> e) & 1u) ? P : 0.0f;
    }
    float4v o0, o1;
#pragma unroll
    for (int e = 0; e < 4; ++e) { o0[e] = p[e]; o1[e] = p[e + 4]; }
    *(float4v*)(arow + kk)     = o0;          // attention output (f32), written once
    *(float4v*)(arow + kk + 4) = o1;
    uint4v uv;
    uv[0] = cvtpk_bf16(p[0], p[1]);
    uv[1] = cvtpk_bf16(p[2], p[3]);
    uv[2] = cvtpk_bf16(p[4], p[5]);
    uv[3] = cvtpk_bf16(p[6], p[7]);
    *(bf16x8*)(AsD + as_off) = __builtin_bit_cast(bf16x8, uv);
  };

  auto COMPUTE = [&](const short* BsD, const short* AsD) {
    bf16x8 af[2][2], bfr[4][2];
#pragma unroll
    for (int i = 0; i < 2; ++i) {
      int row = i * 16 + lr;
#pragma unroll
      for (int s = 0; s < 2; ++s)
        af[i][s] = *(const bf16x8*)(AsD + row * 64 + (((s * 4 + g) ^ (row & 7)) << 3));
    }
#pragma unroll
    for (int j = 0; j < 4; ++j) {
      int col = w * 64 + j * 16 + lr;
#pragma unroll
      for (int s = 0; s < 2; ++s)
        bfr[j][s] = *(const bf16x8*)(BsD + col * 64 + (((s * 4 + g) ^ (col & 7)) << 3));
    }
#pragma unroll
    for (int s = 0; s < 2; ++s)
#pragma unroll
      for (int i = 0; i < 2; ++i)
#pragma unroll
        for (int j = 0; j < 4; ++j)
          acc[i][j] = __builtin_amdgcn_mfma_f32_16x16x32_bf16(af[i][s], bfr[j][s], acc[i][j], 0, 0, 0);
  };

  // prologue
  STAGE(Bs0, As0, 0);
  __syncthreads();
  // 32 K-steps, 2 per iteration (static buffers; one barrier per step)
  for (int t = 0; t < 32; t += 2) {
    STAGE(Bs1, As1, (t + 1) * 64);      // t+1 <= 31 always
    COMPUTE(Bs0, As0);
    __syncthreads();
    if (t + 2 < 32) STAGE(Bs0, As0, (t + 2) * 64);
    COMPUTE(Bs1, As1);
    __syncthreads();
  }

  // C/D: col=lane&15, row=(lane>>4)*4+reg  [m89]
#pragma unroll
  for (int i = 0; i < 2; ++i) {
    int row_base = M0 + i * 16 + 4 * g;
#pragma unroll
    for (int j = 0; j < 4; ++j) {
      int col = w * 64 + j * 16 + lr;
#pragma unroll
      for (int r = 0; r < 4; ++r) {
        float v = acc[i][j][r];
        v = (v > 0.f) ? v : (__expf(v) - 1.f);   // ELU
        C[(long long)(row_base + r) * 256 + col] = v;
      }
    }
  }
}

// ------------- Wh = cast(h_f32) @ W_t^T : m97 structure, A reg-staged f32->bf16 -------------
__global__ __launch_bounds__(256) void gemm_h_kernel(
    const float* __restrict__ A, const short* __restrict__ Bt,
    short* __restrict__ C, int N, int K)
{
  __shared__ short As[128 * 32];
  __shared__ short Bs[128 * 32];
  const int m0 = blockIdx.x * 128, n0 = blockIdx.y * 128;
  const int tid = threadIdx.x;
  const int w = tid >> 6, lane = tid & 63;
  const int wr = w >> 1, wc = w & 1;
  const int g = lane >> 4, lr = lane & 15;

  f32x4 acc[4][4] = {};

  for (int k0 = 0; k0 < K; k0 += 32) {
    __syncthreads();
#pragma unroll
    for (int q = 0; q < 2; ++q) {
      int c = q * 256 + tid;
      int row = c >> 2, kq = (c & 3) << 3;
      const float* ap = A + (long long)(m0 + row) * K + k0 + kq;
      float4v u0 = *(const float4v*)ap;
      float4v u1 = *(const float4v*)(ap + 4);
      uint4v uv;
      uv[0] = cvtpk_bf16(u0[0], u0[1]);
      uv[1] = cvtpk_bf16(u0[2], u0[3]);
      uv[2] = cvtpk_bf16(u1[0], u1[1]);
      uv[3] = cvtpk_bf16(u1[2], u1[3]);
      *(bf16x8*)(As + c * 8) = __builtin_bit_cast(bf16x8, uv);
    }
#pragma unroll
    for (int q = 0; q < 2; ++q) {
      int p = w * 2 + q;
      int c = p * 64 + lane;
      int row = c >> 2, kq = (c & 3) << 3;
      gload16(Bt + (long long)(n0 + row) * K + k0 + kq, Bs + p * 512);
    }
    __syncthreads();

    bf16x8 af[4], bfr[4];
#pragma unroll
    for (int i = 0; i < 4; ++i) {
      af[i]  = *(const bf16x8*)(As + (wr * 64 + i * 16 + lr) * 32 + 8 * g);
      bfr[i] = *(const bf16x8*)(Bs + (wc * 64 + i * 16 + lr) * 32 + 8 * g);
    }
#pragma unroll
    for (int i = 0; i < 4; ++i)
#pragma unroll
      for (int j = 0; j < 4; ++j)
        acc[i][j] = __builtin_amdgcn_mfma_f32_16x16x32_bf16(af[i], bfr[j], acc[i][j], 0, 0, 0);
  }

#pragma unroll
  for (int i = 0; i < 4; ++i) {
    int row_base = m0 + wr * 64 + i * 16 + 4 * g;
#pragma unroll
    for (int j = 0; j < 4; ++j) {
      int col = n0 + wc * 64 + j * 16 + lr;
#pragma unroll
      for (int r = 0; r < 4; ++r)
        C[(long long)(row_base + r) * N + col] = f2bf(acc[i][j][r]);
    }
  }
}

extern "C" void kernel_launch(void* const* d_in, const int* in_sizes, int n_in,
                              void* d_out, int out_size, void* d_ws, size_t ws_size,
                              hipStream_t stream)
{
  const float* h   = (const float*)d_in[0];   // (8,2048,256) f32
  const int*   adj = (const int*)d_in[1];     // (8,2048,2048) int32
  const float* W   = (const float*)d_in[2];   // (256,256) f32
  const float* a   = (const float*)d_in[3];   // (512,1) f32

  float* hp_out   = (float*)d_out;            // elu(h_prime): 4,194,304 f32
  float* attn_out = hp_out + 4194304LL;       // attention: 33,554,432 f32

  // workspace: 21.4 MB (proven-OK layout)
  unsigned char* mask = (unsigned char*)d_ws; // 8*2048*256 = 4.19 MB
  short* W_t  = (short*)(mask + 4194304);     // 256x256 bf16
  short* Wh   = W_t + 65536;                  // 16384x256 bf16
  short* Wh_t = Wh + 4194304;                 // 8 x (256x2048) bf16
  float* e1   = (float*)(Wh_t + 4194304);     // 16384
  float* e2   = e1 + 16384;                   // 16384
  float* Lr   = e2 + 16384;                   // 16384
  float* Dr   = Lr + 16384;                   // 16384

  // 1) W f32 -> W^T bf16
  castT_W_kernel<<<dim3(4, 4), 256, 0, stream>>>(W, W_t);
  // 2) Wh = cast(h) @ W
  gemm_h_kernel<<<dim3(128, 2, 1), 256, 0, stream>>>(h, W_t, Wh, 256, 256);
  // 3) Wh^T per batch
  transpose_bf16_kernel<<<dim3(32, 4, 8), 256, 0, stream>>>(Wh, Wh_t, 2048, 256, 524288LL, 524288LL);
  // 4) e1/e2
  evec_kernel<<<4096, 256, 0, stream>>>(Wh, a, e1, e2);
  // 5) adj -> bitmask + per-row (L,D)  (adj-read-bound, no attn write)
  pack_stats_kernel<<<dim3(2048, 8), 256, 0, stream>>>(adj, e1, e2, mask, Lr, Dr);
  // 6) pipelined pv: recompute P -> attention write + P @ Wh_t + ELU
  pv_kernel<<<512, 256, 0, stream>>>(mask, e1, e2, Lr, Dr, Wh_t, attn_out, hp_out);
}